// Round 10
// baseline (675.143 us; speedup 1.0000x reference)
//
#include <hip/hip_runtime.h>
#include <hip/hip_bf16.h>
#include <hip/hip_fp16.h>
#include <math.h>

#define BB 16
#define HH 56
#define WW 56
#define CC0 192
#define NHH 6
#define HDD 32
#define NPOS (HH*WW)       // 3136
#define MROWS (BB*NPOS)    // 50176
#define C4 (4*CC0)         // 768

typedef __hip_bfloat16 bf16;
typedef __half f16;
typedef short short8 __attribute__((ext_vector_type(8)));
typedef short short4v __attribute__((ext_vector_type(4)));
typedef float f32x4 __attribute__((ext_vector_type(4)));
typedef float f32x2 __attribute__((ext_vector_type(2)));
typedef unsigned int u32;
typedef u32 u32x4 __attribute__((ext_vector_type(4)));
typedef u32 u32x2 __attribute__((ext_vector_type(2)));

__device__ __forceinline__ float b2f(bf16 v){ return __bfloat162float(v); }
__device__ __forceinline__ bf16 f2b(float v){ return __float2bfloat16(v); }
__device__ __forceinline__ short f2s(float v){ bf16 b = __float2bfloat16(v); return *(short*)&b; }
__device__ __forceinline__ float s2f(short s){ bf16 b; *(short*)&b = s; return __bfloat162float(b); }
__device__ __forceinline__ float tof(float v){ return v; }
__device__ __forceinline__ float tof(f16 v){ return __half2float(v); }
// unpack 2 bf16 (packed in u32) -> f32x2; exact (bit placement into high 16)
__device__ __forceinline__ f32x2 bfp(u32 u){
  union { u32 q; float f; } lo, hi;
  lo.q = u << 16; hi.q = u & 0xffff0000u;
  return (f32x2){lo.f, hi.f};
}
__device__ __forceinline__ float fast_gelu(float x){
  float u = 1.5957691216f * (x + 0.044715f*x*x*x);
  float t = 1.f - 2.f/(__expf(u) + 1.f);
  return 0.5f*x*(1.f + t);
}
// XCD-aware swizzle (verified R7: mdw_ln FETCH 164->38 MB)
__device__ __forceinline__ int swz8(int bid, int nblk){
  return (bid & 7) * (nblk >> 3) + (bid >> 3);
}

// ---------------- setup: weights f32->bf16 W^T, RoPE tables, zero KMEAN/KV ----------------
// R16: fused convert_weights + rope_tables + 2 memsets into one dispatch.
__global__ __launch_bounds__(256) void setup_kernel(
    const float* __restrict__ w0, const float* __restrict__ w1,
    const float* __restrict__ w2, const float* __restrict__ w3,
    const float* __restrict__ w4, const float* __restrict__ w5,
    short* __restrict__ dst, float* __restrict__ cosT, float* __restrict__ sinT,
    float* __restrict__ zbase){
  int bid = blockIdx.x;
  if (bid < 468){
    int e = (bid*256 + threadIdx.x)*4;
    const float* src; int K, N, off;
    if      (e <  36864){ src=w0; K=192; N=192; off=0; }
    else if (e <  73728){ src=w1; K=192; N=192; off=36864; }
    else if (e < 147456){ src=w2; K=192; N=384; off=73728; }
    else if (e < 184320){ src=w3; K=192; N=192; off=147456; }
    else if (e < 331776){ src=w4; K=192; N=768; off=184320; }
    else                { src=w5; K=768; N=192; off=331776; }
    int le = e - off;
    int n = le / K, k = le % K;
    short4v o;
    #pragma unroll
    for (int l = 0; l < 4; ++l) o[l] = f2s(src[(size_t)(k+l)*N + n]);
    *(short4v*)(dst + e) = o;
  } else if (bid < 468 + 1176){
    int idx = (bid-468)*256 + threadIdx.x;
    int t = idx % 96; int ij = idx / 96; int i = ij / WW; int j = ij % WW;
    int kk = (t < 48) ? t : (t - 48);
    float th = expf(-(float)kk * 0.19188209108283716f);
    float pos = (t < 48) ? (float)i : (float)j;
    float ang = pos * th;
    cosT[idx] = cosf(ang);
    sinT[idx] = sinf(ang);
  } else {
    int zi = ((bid-1644)*256 + threadIdx.x)*4;
    if (zi < 101376) *(f32x4*)(zbase + zi) = (f32x4){0.f,0.f,0.f,0.f};
  }
}

// ---------------- fused cpe dwconv + residual + LN192 (4 pos/wave) ----------------
// R11 structure; R15: templated input (f32 for x, fp16 for x2 spine),
// x1out stored fp16 (spine traffic halved; storage rounding only, accum f32).
template<typename TIN>
__global__ __launch_bounds__(256) void cpe_ln_kernel(const TIN* __restrict__ in,
    const float* __restrict__ w, const float* __restrict__ bias,
    const float* __restrict__ g, const float* __restrict__ bb,
    f16* __restrict__ x1out, bf16* __restrict__ xnout){
  int wv = threadIdx.x >> 6, lane = threadIdx.x & 63;
  int grp = swz8(blockIdx.x, gridDim.x)*4 + wv;   // group of 4 positions
  int pos0 = grp * 4;
  int b = pos0 / NPOS; int ij = pos0 % NPOS; int i = ij / WW; int j0 = ij % WW;
  int c = lane * 3;
  float acc[4][3];
  {
    float b0 = bias[c], b1 = bias[c+1], b2 = bias[c+2];
    #pragma unroll
    for (int p = 0; p < 4; ++p){ acc[p][0]=b0; acc[p][1]=b1; acc[p][2]=b2; }
  }
  float fc[4][3];                       // center-row in values (residual + LN re-add)
  bool leftOK  = (j0 > 0);
  bool rightOK = (j0 + 4 < WW);
  int base_i = (b*NPOS + i*WW + j0)*CC0 + c;   // elem offset (<9.7M, 32-bit safe)

  #pragma unroll
  for (int di = 0; di < 3; ++di){
    int ii = i + di - 1;
    if (ii < 0 || ii >= HH) continue;   // wave-uniform; OOB row contributes 0
    int rb = base_i + (di-1)*(WW*CC0);
    float wt[3][3];
    #pragma unroll
    for (int dj = 0; dj < 3; ++dj){
      const float* wp = w + (di*3 + dj)*CC0 + c;
      wt[dj][0] = wp[0]; wt[dj][1] = wp[1]; wt[dj][2] = wp[2];
    }
    if (leftOK){   // col 0: only (p=0, dj=0)
      const TIN* ip = in + rb - CC0;
      float d0 = tof(ip[0]), d1 = tof(ip[1]), d2 = tof(ip[2]);
      acc[0][0] += d0*wt[0][0]; acc[0][1] += d1*wt[0][1]; acc[0][2] += d2*wt[0][2];
    }
    #pragma unroll
    for (int col = 1; col <= 4; ++col){   // always in-bounds (j0 <= 52)
      const TIN* ip = in + rb + (col-1)*CC0;
      float d0 = tof(ip[0]), d1 = tof(ip[1]), d2 = tof(ip[2]);
      if (di == 1){ fc[col-1][0] = d0; fc[col-1][1] = d1; fc[col-1][2] = d2; }
      #pragma unroll
      for (int dj = 0; dj < 3; ++dj){
        int p = col - dj;
        if (p >= 0 && p < 4){
          acc[p][0] += d0*wt[dj][0]; acc[p][1] += d1*wt[dj][1]; acc[p][2] += d2*wt[dj][2];
        }
      }
    }
    if (rightOK){  // col 5: only (p=3, dj=2)
      const TIN* ip = in + rb + 4*CC0;
      float d0 = tof(ip[0]), d1 = tof(ip[1]), d2 = tof(ip[2]);
      acc[3][0] += d0*wt[2][0]; acc[3][1] += d1*wt[2][1]; acc[3][2] += d2*wt[2][2];
    }
  }
  float gv0 = g[c], gv1 = g[c+1], gv2 = g[c+2];
  float bv0 = bb[c], bv1 = bb[c+1], bv2 = bb[c+2];
  #pragma unroll
  for (int p = 0; p < 4; ++p){
    float v0 = fc[p][0] + acc[p][0];
    float v1 = fc[p][1] + acc[p][1];
    float v2 = fc[p][2] + acc[p][2];
    int base = (pos0 + p)*CC0 + c;
    f16* xp = x1out + base;
    xp[0] = __float2half(v0); xp[1] = __float2half(v1); xp[2] = __float2half(v2);
    float s = v0+v1+v2, q = v0*v0+v1*v1+v2*v2;
    #pragma unroll
    for (int m = 1; m < 64; m <<= 1){ s += __shfl_xor(s, m, 64); q += __shfl_xor(q, m, 64); }
    float mean = s * (1.f/CC0);
    float rstd = rsqrtf(q * (1.f/CC0) - mean*mean + 1e-5f);
    bf16* op = xnout + base;
    op[0] = f2b((v0-mean)*rstd*gv0 + bv0);
    op[1] = f2b((v1-mean)*rstd*gv1 + bv1);
    op[2] = f2b((v2-mean)*rstd*gv2 + bv2);
  }
}

// ---------------- depthwise 3x3 conv, 4 pos/thread, packed f32x2 (R12) ----------------
// MODE 1: out(bf16) = silu(conv+bias)   MODE 2: out(bf16) += conv+bias (RMW)
template<int MODE>
__global__ __launch_bounds__(256) void dwconv4(const bf16* __restrict__ in,
    const float* __restrict__ w, const float* __restrict__ bias, void* __restrict__ out){
  int idx = swz8(blockIdx.x, gridDim.x)*256 + threadIdx.x;
  int cg = idx % 24; int quad = idx / 24;
  int pos0 = quad * 4;
  int b = pos0 / NPOS; int ij = pos0 % NPOS; int i = ij / WW; int j0 = ij % WW;
  int cb = cg * 8;
  const short* fp = (const short*)in;
  f32x2 acc[4][4];
  {
    f32x2 bv0 = *(const f32x2*)(bias + cb);
    f32x2 bv1 = *(const f32x2*)(bias + cb + 2);
    f32x2 bv2 = *(const f32x2*)(bias + cb + 4);
    f32x2 bv3 = *(const f32x2*)(bias + cb + 6);
    #pragma unroll
    for (int p = 0; p < 4; ++p){ acc[p][0]=bv0; acc[p][1]=bv1; acc[p][2]=bv2; acc[p][3]=bv3; }
  }
  bool leftOK  = (j0 > 0);
  bool rightOK = (j0 + 4 < WW);
  int base_i = (b*NPOS + i*WW + j0)*CC0 + cb;   // elem offset (<9.7M, 32-bit safe)

  #pragma unroll
  for (int di = 0; di < 3; ++di){
    int ii = i + di - 1;
    if (ii < 0 || ii >= HH) continue;           // per-lane; OOB row contributes 0
    int rb = base_i + (di-1)*(WW*CC0);
    const float* wr = w + (di*3)*CC0 + cb;
    f32x2 wt[3][4];
    #pragma unroll
    for (int dj = 0; dj < 3; ++dj){
      #pragma unroll
      for (int l = 0; l < 4; ++l) wt[dj][l] = *(const f32x2*)(wr + dj*CC0 + 2*l);
    }
    if (leftOK){   // col 0: only (p=0, dj=0)
      u32x4 x = *(const u32x4*)(fp + rb - CC0);
      #pragma unroll
      for (int l = 0; l < 4; ++l) acc[0][l] += bfp(x[l])*wt[0][l];
    }
    #pragma unroll
    for (int col = 1; col <= 4; ++col){          // always in-bounds (j0 <= 52)
      u32x4 x = *(const u32x4*)(fp + rb + (col-1)*CC0);
      f32x2 dv[4];
      #pragma unroll
      for (int l = 0; l < 4; ++l) dv[l] = bfp(x[l]);
      #pragma unroll
      for (int dj = 0; dj < 3; ++dj){
        int p = col - dj;
        if (p >= 0 && p < 4){
          #pragma unroll
          for (int l = 0; l < 4; ++l) acc[p][l] += dv[l]*wt[dj][l];
        }
      }
    }
    if (rightOK){  // col 5: only (p=3, dj=2)
      u32x4 x = *(const u32x4*)(fp + rb + 4*CC0);
      #pragma unroll
      for (int l = 0; l < 4; ++l) acc[3][l] += bfp(x[l])*wt[2][l];
    }
  }
  #pragma unroll
  for (int p = 0; p < 4; ++p){
    int oidx = (pos0 + p)*CC0 + cb;
    short8 o;
    if constexpr (MODE == 1){
      #pragma unroll
      for (int l = 0; l < 4; ++l){
        float a0 = acc[p][l][0], a1 = acc[p][l][1];
        o[2*l]   = f2s(a0/(1.f + expf(-a0)));
        o[2*l+1] = f2s(a1/(1.f + expf(-a1)));
      }
    } else {
      u32x4 r = *(const u32x4*)((const short*)out + oidx);
      #pragma unroll
      for (int l = 0; l < 4; ++l){
        f32x2 s = bfp(r[l]) + acc[p][l];
        o[2*l] = f2s(s[0]); o[2*l+1] = f2s(s[1]);
      }
    }
    *(short8*)((short*)out + oidx) = o;
  }
}

// ---------------- MFMA GEMM: A [M,K] bf16-ish @ W^T [N,K] bf16 + bias ----------------
// R17: grid REVERTED to blockIdx.x = M-tile (fastest) — XCD round-robin then
// partitions A-tiles across L2s and the tiny B-panel is resident everywhere.
// (R16's swap put same-A blocks on different XCDs: A fetched into many L2s,
// +15us regression.) NB stays templated: 128 for fc1 halves N-sweeps.
// ALOAD: 0 = bf16 direct, 1 = bf16 * bf16 product
// EPI: 0 = bf16, 1 = silu->bf16, 2 = elu+1 split ->bf16,
//      3 = +addf(f16) -> f32, 4 = split silu/plain (addf = 2nd bias f32),
//      5 = +addf(f16) -> f16.  EPI 2/4 require NB=64 (n0 may not straddle 192).
#define BM 256
#define BK 32
#define LDA 40
template<int K, int N, int NB, int ALOAD, int EPI>
__global__ __launch_bounds__(256) void mfma_gemm(
    const void* __restrict__ a0v, const void* __restrict__ a1v,
    const short* __restrict__ wT, const float* __restrict__ bias,
    const void* __restrict__ addf, void* __restrict__ out0, void* __restrict__ out1){
  __shared__ short As[BM*LDA];
  __shared__ short Bs[NB*LDA];
  constexpr int NT = NB/16;
  int tid = threadIdx.x;
  int wave = tid >> 6, lane = tid & 63;
  size_t m0 = (size_t)blockIdx.x * BM;
  int n0 = blockIdx.y * NB;
  int wm = wave * 64;
  int am = lane & 15, ak = (lane >> 4) * 8;

  f32x4 acc[4][NT];
  #pragma unroll
  for (int mt = 0; mt < 4; ++mt)
    #pragma unroll
    for (int nt = 0; nt < NT; ++nt)
      acc[mt][nt] = (f32x4){0.f,0.f,0.f,0.f};

  for (int k0 = 0; k0 < K; k0 += BK){
    if constexpr (ALOAD == 0){
      const short* A = (const short*)a0v;
      #pragma unroll
      for (int it = 0; it < 4; ++it){
        int idx = it*256 + tid;
        int row = idx >> 2; int ko = (idx & 3) * 8;
        short8 v = *(const short8*)(A + (m0 + row)*(size_t)K + k0 + ko);
        *(short8*)&As[row*LDA + ko] = v;
      }
    } else {
      const short* A0p = (const short*)a0v;
      const short* A1p = (const short*)a1v;
      #pragma unroll
      for (int it = 0; it < 4; ++it){
        int idx = it*256 + tid;
        int row = idx >> 2; int ko = (idx & 3) * 8;
        size_t off = (m0 + row)*(size_t)K + k0 + ko;
        short8 va = *(const short8*)(A0p + off);
        short8 vb = *(const short8*)(A1p + off);
        short8 o;
        #pragma unroll
        for (int l = 0; l < 8; ++l) o[l] = f2s(s2f(va[l]) * s2f(vb[l]));
        *(short8*)&As[row*LDA + ko] = o;
      }
    }
    #pragma unroll
    for (int bt = 0; bt < NB/64; ++bt){
      int idx2 = bt*256 + tid;
      int row = idx2 >> 2; int ko = (idx2 & 3) * 8;
      short8 v = *(const short8*)(wT + (size_t)(n0 + row)*K + k0 + ko);
      *(short8*)&Bs[row*LDA + ko] = v;
    }
    __syncthreads();
    short8 af[4], bfr[NT];
    #pragma unroll
    for (int mt = 0; mt < 4; ++mt) af[mt] = *(short8*)&As[(wm + mt*16 + am)*LDA + ak];
    #pragma unroll
    for (int nt = 0; nt < NT; ++nt) bfr[nt] = *(short8*)&Bs[(nt*16 + am)*LDA + ak];
    #pragma unroll
    for (int mt = 0; mt < 4; ++mt)
      #pragma unroll
      for (int nt = 0; nt < NT; ++nt)
        acc[mt][nt] = __builtin_amdgcn_mfma_f32_16x16x32_bf16(af[mt], bfr[nt], acc[mt][nt], 0, 0, 0);
    __syncthreads();
  }

  int cn = lane & 15;
  int cr = (lane >> 4) * 4;
  #pragma unroll
  for (int mt = 0; mt < 4; ++mt){
    #pragma unroll
    for (int nt = 0; nt < NT; ++nt){
      int gn = n0 + nt*16 + cn;
      float bv;
      if constexpr (EPI == 4) bv = (n0 < CC0) ? bias[gn] : ((const float*)addf)[gn - CC0];
      else bv = bias[gn];
      #pragma unroll
      for (int r = 0; r < 4; ++r){
        size_t gm = m0 + wm + mt*16 + cr + r;
        float v = acc[mt][nt][r] + bv;
        if constexpr (EPI == 0){
          ((bf16*)out0)[gm*N + gn] = f2b(v);
        } else if constexpr (EPI == 1){
          ((bf16*)out0)[gm*N + gn] = f2b(v / (1.f + expf(-v)));
        } else if constexpr (EPI == 2){
          float rv = (v > 0.f) ? (v + 1.f) : expf(v);
          if (n0 < CC0) ((bf16*)out0)[gm*CC0 + gn] = f2b(rv);
          else          ((bf16*)out1)[gm*CC0 + (gn - CC0)] = f2b(rv);
        } else if constexpr (EPI == 4){
          if (n0 < CC0) ((bf16*)out0)[gm*CC0 + gn] = f2b(v / (1.f + expf(-v)));
          else          ((bf16*)out1)[gm*CC0 + (gn - CC0)] = f2b(v);
        } else if constexpr (EPI == 5){
          ((f16*)out0)[gm*N + gn] =
            __float2half(__half2float(((const f16*)addf)[gm*N + gn]) + v);
        } else {
          ((float*)out0)[gm*N + gn] =
            __half2float(((const f16*)addf)[gm*N + gn]) + v;
        }
      }
    }
  }
}

// ---------------- kv + kmean fused (R15), 14 N-chunks ----------------
#define KVCH 14
__global__ __launch_bounds__(256) void kv_kernel(const bf16* __restrict__ kbuf,
    const bf16* __restrict__ hbuf, const float* __restrict__ cosT,
    const float* __restrict__ sinT, float* __restrict__ kv,
    float* __restrict__ kmean){
  int bi = blockIdx.x;
  int chunk = bi % KVCH; bi /= KVCH;
  int h = bi % NHH; int b = bi / NHH;
  int tid = threadIdx.x;
  int r8 = tid >> 5, lane = tid & 31;
  __shared__ float krs[8][32];
  __shared__ float vvs[8][32];
  int d = tid >> 3; int ebase = (tid & 7) * 4;
  float a0 = 0.f, a1 = 0.f, a2 = 0.f, a3 = 0.f;
  float ksum = 0.f;
  int c = h*HDD + lane;
  int t = c >> 1;
  bool odd = (lane & 1);
  for (int step = 0; step < NPOS/(KVCH*8); ++step){
    int n = chunk*(NPOS/KVCH) + step*8 + r8;
    size_t row = (size_t)b*NPOS + n;
    float kc = b2f(kbuf[row*CC0 + c]);
    float kp = b2f(kbuf[row*CC0 + (c ^ 1)]);
    ksum += kc;
    float cs = cosT[(size_t)n*96 + t], sn = sinT[(size_t)n*96 + t];
    krs[r8][lane] = odd ? (cs*kc + sn*kp) : (cs*kc - sn*kp);
    vvs[r8][lane] = b2f(hbuf[row*CC0 + c]);
    __syncthreads();
    #pragma unroll
    for (int nn = 0; nn < 8; ++nn){
      float kk2 = krs[nn][d];
      a0 += kk2 * vvs[nn][ebase+0];
      a1 += kk2 * vvs[nn][ebase+1];
      a2 += kk2 * vvs[nn][ebase+2];
      a3 += kk2 * vvs[nn][ebase+3];
    }
    __syncthreads();
  }
  const float invN = 1.f/NPOS;
  ksum += __shfl_xor(ksum, 32, 64);
  if ((tid & 32) == 0) atomicAdd(&kmean[b*CC0 + c], ksum * invN);
  float* kvp = kv + (((size_t)(b*NHH + h)*HDD + d)*HDD) + ebase;
  atomicAdd(kvp+0, a0*invN);
  atomicAdd(kvp+1, a1*invN);
  atomicAdd(kvp+2, a2*invN);
  atomicAdd(kvp+3, a3*invN);
}

// ---------------- fused attention via MFMA (R14) ----------------
__global__ __launch_bounds__(256) void attn_mfma(const bf16* __restrict__ q,
    const float* __restrict__ kmean, const float* __restrict__ kv,
    const float* __restrict__ cosT, const float* __restrict__ sinT,
    bf16* __restrict__ out){
  int w = threadIdx.x >> 6, lane = threadIdx.x & 63;
  int idx = blockIdx.x*4 + w;            // tile index
  int mt = idx % (NPOS/16);              // 196 M-tiles
  int rest = idx / (NPOS/16);
  int h = rest % NHH; int b = rest / NHH;
  int r15 = lane & 15, kq = (lane >> 4) * 8;
  int n = mt*16 + r15;
  size_t row = (size_t)b*NPOS + n;
  int ch = h*HDD + kq;
  short8 q8 = *(const short8*)((const short*)q + row*CC0 + ch);
  float qf[8];
  #pragma unroll
  for (int j = 0; j < 8; ++j) qf[j] = s2f(q8[j]);
  const float* kmp = kmean + b*CC0 + ch;
  f32x4 km0 = *(const f32x4*)(kmp);
  f32x4 km1 = *(const f32x4*)(kmp + 4);
  float pm = qf[0]*km0[0]+qf[1]*km0[1]+qf[2]*km0[2]+qf[3]*km0[3]
           + qf[4]*km1[0]+qf[5]*km1[1]+qf[6]*km1[2]+qf[7]*km1[3];
  pm += __shfl_xor(pm, 16, 64);
  pm += __shfl_xor(pm, 32, 64);
  float z = 1.f/(pm + 1e-6f);
  int t0 = h*16 + (kq >> 1);
  f32x4 cs = *(const f32x4*)(cosT + n*96 + t0);
  f32x4 sn = *(const f32x4*)(sinT + n*96 + t0);
  short8 af;
  #pragma unroll
  for (int u = 0; u < 4; ++u){
    float e = cs[u]*qf[2*u]   - sn[u]*qf[2*u+1];
    float o = cs[u]*qf[2*u+1] + sn[u]*qf[2*u];
    af[2*u] = f2s(e); af[2*u+1] = f2s(o);
  }
  const float* kvp = kv + (size_t)(b*NHH + h)*HDD*HDD + kq*HDD + r15;
  short8 bf0, bf1;
  #pragma unroll
  for (int j = 0; j < 8; ++j){
    bf0[j] = f2s(kvp[j*HDD]);
    bf1[j] = f2s(kvp[j*HDD + 16]);
  }
  f32x4 acc0 = (f32x4){0.f,0.f,0.f,0.f};
  f32x4 acc1 = (f32x4){0.f,0.f,0.f,0.f};
  acc0 = __builtin_amdgcn_mfma_f32_16x16x32_bf16(af, bf0, acc0, 0, 0, 0);
  acc1 = __builtin_amdgcn_mfma_f32_16x16x32_bf16(af, bf1, acc1, 0, 0, 0);
  int rbase = (lane >> 4) * 4;
  #pragma unroll
  for (int r = 0; r < 4; ++r){
    float zz = __shfl(z, rbase + r, 64);
    size_t orow = (size_t)b*NPOS + mt*16 + rbase + r;
    out[orow*CC0 + ch - kq + r15]      = f2b(acc0[r]*zz);
    out[orow*CC0 + ch - kq + r15 + 16] = f2b(acc1[r]*zz);
  }
}

// ---------------- fused mdw dwconv + n1/n2/n3 LN chain + gelu (XCD-swizzled) ----------------
// R16: all 6 column loads of a conv row issued BEFORE any FMA (latency overlap);
// edge columns zero-filled (branch-free, 0-contribution == SAME padding).
// R10 packed-f32 math retained.
__global__ __launch_bounds__(256) void mdw_ln_kernel(const bf16* __restrict__ f1,
    const float* __restrict__ w, const float* __restrict__ bias,
    const float* __restrict__ g1, const float* __restrict__ b1,
    const float* __restrict__ g2, const float* __restrict__ b2,
    const float* __restrict__ g3, const float* __restrict__ b3,
    bf16* __restrict__ out){
  int wv = threadIdx.x >> 6, lane = threadIdx.x & 63;
  int grp = swz8(blockIdx.x, gridDim.x)*4 + wv;   // group of 4 positions
  int pos0 = grp * 4;
  int b = pos0 / NPOS; int ij = pos0 % NPOS; int i = ij / WW; int j0 = ij % WW;
  int c0 = lane * 8;
  int c1 = 512 + lane * 4;
  const short* fp = (const short*)f1;

  f32x2 acc2[4][6];
  {
    f32x2 bv[6];
    #pragma unroll
    for (int l = 0; l < 4; ++l) bv[l] = *(const f32x2*)(bias + c0 + 2*l);
    bv[4] = *(const f32x2*)(bias + c1);
    bv[5] = *(const f32x2*)(bias + c1 + 2);
    #pragma unroll
    for (int p = 0; p < 4; ++p)
      #pragma unroll
      for (int l = 0; l < 6; ++l) acc2[p][l] = bv[l];
  }
  u32x4 fca[4]; u32x2 fcb[4];   // center-row f1, packed bf16
  bool leftOK  = (j0 > 0);
  bool rightOK = (j0 + 4 < WW);
  int base_i = (b*NPOS + i*WW + j0)*C4;   // elem offset (<38.6M, 32-bit safe)

  #pragma unroll
  for (int di = 0; di < 3; ++di){
    int ii = i + di - 1;
    if (ii < 0 || ii >= HH) continue;     // wave-uniform; OOB row contributes 0
    int rb = base_i + (di-1)*(WW*C4);
    // batch-issue ALL 6 column loads before any FMA (R16)
    u32x4 xa6[6]; u32x2 xb6[6];
    if (leftOK){ xa6[0] = *(const u32x4*)(fp + rb - C4 + c0);
                 xb6[0] = *(const u32x2*)(fp + rb - C4 + c1); }
    else       { xa6[0] = (u32x4){0,0,0,0}; xb6[0] = (u32x2){0,0}; }
    #pragma unroll
    for (int col = 1; col <= 4; ++col){
      xa6[col] = *(const u32x4*)(fp + rb + (col-1)*C4 + c0);
      xb6[col] = *(const u32x2*)(fp + rb + (col-1)*C4 + c1);
    }
    if (rightOK){ xa6[5] = *(const u32x4*)(fp + rb + 4*C4 + c0);
                  xb6[5] = *(const u32x2*)(fp + rb + 4*C4 + c1); }
    else        { xa6[5] = (u32x4){0,0,0,0}; xb6[5] = (u32x2){0,0}; }
    f32x2 wt2[3][6];
    #pragma unroll
    for (int dj = 0; dj < 3; ++dj){
      const float* wp = w + (di*3 + dj)*C4;
      #pragma unroll
      for (int l = 0; l < 4; ++l) wt2[dj][l] = *(const f32x2*)(wp + c0 + 2*l);
      wt2[dj][4] = *(const f32x2*)(wp + c1);
      wt2[dj][5] = *(const f32x2*)(wp + c1 + 2);
    }
    #pragma unroll
    for (int col = 0; col < 6; ++col){
      if (di == 1 && col >= 1 && col <= 4){ fca[col-1] = xa6[col]; fcb[col-1] = xb6[col]; }
      f32x2 dv[6];
      dv[0]=bfp(xa6[col][0]); dv[1]=bfp(xa6[col][1]);
      dv[2]=bfp(xa6[col][2]); dv[3]=bfp(xa6[col][3]);
      dv[4]=bfp(xb6[col][0]); dv[5]=bfp(xb6[col][1]);
      #pragma unroll
      for (int dj = 0; dj < 3; ++dj){
        int p = col - dj;
        if (p >= 0 && p < 4){
          #pragma unroll
          for (int l = 0; l < 6; ++l) acc2[p][l] += dv[l]*wt2[dj][l];
        }
      }
    }
  }
  // v = dw + f1 (center residual)
  #pragma unroll
  for (int p = 0; p < 4; ++p){
    #pragma unroll
    for (int l = 0; l < 4; ++l) acc2[p][l] += bfp(fca[p][l]);
    acc2[p][4] += bfp(fcb[p][0]);
    acc2[p][5] += bfp(fcb[p][1]);
  }

  const float* gs[3] = {g1, g2, g3};
  const float* bs[3] = {b1, b2, b3};
  #pragma unroll
  for (int pass = 0; pass < 3; ++pass){
    f32x2 gv[6], bvv[6];
    #pragma unroll
    for (int l = 0; l < 4; ++l){
      gv[l]  = *(const f32x2*)(gs[pass] + c0 + 2*l);
      bvv[l] = *(const f32x2*)(bs[pass] + c0 + 2*l);
    }
    gv[4]  = *(const f32x2*)(gs[pass] + c1);  gv[5]  = *(const f32x2*)(gs[pass] + c1 + 2);
    bvv[4] = *(const f32x2*)(bs[pass] + c1);  bvv[5] = *(const f32x2*)(bs[pass] + c1 + 2);
    #pragma unroll
    for (int p = 0; p < 4; ++p){
      f32x2 s2 = acc2[p][0];
      f32x2 q2 = acc2[p][0]*acc2[p][0];
      #pragma unroll
      for (int l = 1; l < 6; ++l){ s2 += acc2[p][l]; q2 += acc2[p][l]*acc2[p][l]; }
      float s = s2[0]+s2[1], q = q2[0]+q2[1];
      #pragma unroll
      for (int m = 1; m < 64; m <<= 1){ s += __shfl_xor(s, m, 64); q += __shfl_xor(q, m, 64); }
      float mean = s * (1.f/C4);
      float rstd = rsqrtf(q * (1.f/C4) - mean*mean + 1e-5f);
      #pragma unroll
      for (int l = 0; l < 6; ++l){
        f32x2 rg = gv[l]*rstd;
        f32x2 t  = acc2[p][l] - mean;
        acc2[p][l] = t*rg + bvv[l];
      }
      if (pass < 2){
        #pragma unroll
        for (int l = 0; l < 4; ++l) acc2[p][l] += bfp(fca[p][l]);
        acc2[p][4] += bfp(fcb[p][0]);
        acc2[p][5] += bfp(fcb[p][1]);
      }
    }
  }
  #pragma unroll
  for (int p = 0; p < 4; ++p){
    short8 o0; short4v o1;
    #pragma unroll
    for (int l = 0; l < 4; ++l){
      o0[2*l]   = f2s(fast_gelu(acc2[p][l][0]));
      o0[2*l+1] = f2s(fast_gelu(acc2[p][l][1]));
    }
    o1[0] = f2s(fast_gelu(acc2[p][4][0]));
    o1[1] = f2s(fast_gelu(acc2[p][4][1]));
    o1[2] = f2s(fast_gelu(acc2[p][5][0]));
    o1[3] = f2s(fast_gelu(acc2[p][5][1]));
    int ob = (pos0 + p)*C4;
    *(short8*)((short*)out + ob + c0) = o0;
    *(short4v*)((short*)out + ob + c1) = o1;
  }
}

extern "C" void kernel_launch(void* const* d_in, const int* in_sizes, int n_in,
                              void* d_out, int out_size, void* d_ws, size_t ws_size,
                              hipStream_t stream){
  (void)in_sizes; (void)n_in; (void)out_size; (void)ws_size;
  const float* X      = (const float*)d_in[0];
  const float* cpe1_w = (const float*)d_in[1];
  const float* cpe1_b = (const float*)d_in[2];
  const float* n1g    = (const float*)d_in[3];
  const float* n1b    = (const float*)d_in[4];
  const float* in_w   = (const float*)d_in[5];
  const float* in_b   = (const float*)d_in[6];
  const float* actp_w = (const float*)d_in[7];
  const float* actp_b = (const float*)d_in[8];
  const float* dwc_w  = (const float*)d_in[9];
  const float* dwc_b  = (const float*)d_in[10];
  const float* qk_w   = (const float*)d_in[11];
  const float* qk_b   = (const float*)d_in[12];
  const float* lepe_w = (const float*)d_in[13];
  const float* lepe_b = (const float*)d_in[14];
  const float* outp_w = (const float*)d_in[15];
  const float* outp_b = (const float*)d_in[16];
  const float* cpe2_w = (const float*)d_in[17];
  const float* cpe2_b = (const float*)d_in[18];
  const float* n2g    = (const float*)d_in[19];
  const float* n2b    = (const float*)d_in[20];
  const float* fc1_w  = (const float*)d_in[21];
  const float* fc1_b  = (const float*)d_in[22];
  const float* mdw_w  = (const float*)d_in[23];
  const float* mdw_b  = (const float*)d_in[24];
  const float* fc2_w  = (const float*)d_in[25];
  const float* fc2_b  = (const float*)d_in[26];
  const float* mn1g   = (const float*)d_in[27];
  const float* mn1b   = (const float*)d_in[28];
  const float* mn2g   = (const float*)d_in[29];
  const float* mn2b   = (const float*)d_in[30];
  const float* mn3g   = (const float*)d_in[31];
  const float* mn3b   = (const float*)d_in[32];

  char* ws = (char*)d_ws;
  const size_t SZF = (size_t)MROWS*CC0*4;
  const size_t SZB = (size_t)MROWS*CC0*2;
  f16* A0h = (f16*)(ws);                    // x1 -> x3 (fp16 residual spine, R15)
  char* base2 = ws + SZF;
  bf16* BQ = (bf16*)(base2 + 0*SZB);        // q
  bf16* BKb= (bf16*)(base2 + 1*SZB);        // k
  bf16* BA = (bf16*)(base2 + 2*SZB);        // attn (+lepe)
  bf16* B1 = (bf16*)(base2 + 3*SZB);        // act_res
  bf16* B0 = (bf16*)(base2 + 4*SZB);        // xn -> xm
  bf16* B2 = (bf16*)(base2 + 5*SZB);        // t
  bf16* B3 = (bf16*)(base2 + 6*SZB);        // h
  f16*  A1h = (f16*)(base2);                // x2 (fp16) overlays BQ
  bf16*  F1 = (bf16*)(base2);               // f1 overlays slots 0-3
  bf16*  DW = (bf16*)(base2 + 4*SZB);       // gelu(n3) overlays slots 4-7
  short* WT = (short*)(base2 + 8*SZB);
  char* tail = (char*)(WT + 479232 + 64);
  float* KMEAN = (float*)tail;                 tail += (size_t)BB*CC0*4;
  float* KV    = (float*)tail;                 tail += (size_t)BB*NHH*HDD*HDD*4;
  float* COS   = (float*)tail;                 tail += (size_t)NPOS*96*4;
  float* SIN   = (float*)tail;

  const short* actpT = WT + 0;       // rows 0..191 = actp^T; rows 192..383 = in^T (contiguous)
  const short* qkT   = WT + 73728;
  const short* outpT = WT + 147456;
  const short* fc1T  = WT + 184320;
  const short* fc2T  = WT + 331776;

  const int GPOS16 = MROWS/16;             // 3136 (8 | G) — 4 waves x 4 pos
  const int GDW4   = (MROWS/4)*24/256;     // 1176 (8 | G) — dwconv4 grid
  const int GATT   = (BB*NHH*(NPOS/16))/4; // 4704 — attn_mfma grid (4 tiles/block)

  // 0. setup: weight convert + RoPE tables + zero KMEAN/KV (one dispatch, R16)
  setup_kernel<<<1743, 256, 0, stream>>>(actp_w, in_w, qk_w, outp_w, fc1_w, fc2_w,
                                         WT, COS, SIN, KMEAN);
  // 1+2. x1 = x + cpe1(x); xn = LN(x1)  (fused, 4 pos/wave, fp16 x1)
  cpe_ln_kernel<float><<<GPOS16, 256, 0, stream>>>(X, cpe1_w, cpe1_b, n1g, n1b, A0h, B0);
  // 3+4 fused. [act_res = silu(xn@actp)] ++ [t = xn@in_w + b]  (one N=384 GEMM)
  mfma_gemm<CC0,2*CC0,64,0,4><<<dim3(MROWS/BM,2*CC0/64), 256, 0, stream>>>(B0, nullptr, actpT, actp_b, in_b, B1, B2);
  // 5. h = silu(dwc(t))
  dwconv4<1><<<GDW4, 256, 0, stream>>>(B2, dwc_w, dwc_b, B3);
  // 6. qk = h@qk_w; q->BQ, k->BK (bf16, elu+1)
  mfma_gemm<CC0,2*CC0,64,0,2><<<dim3(MROWS/BM,2*CC0/64), 256, 0, stream>>>(B3, nullptr, qkT, qk_b, nullptr, BQ, BKb);
  // 7. kv + kmean (fused, R15)
  kv_kernel<<<BB*NHH*KVCH, 256, 0, stream>>>(BKb, B3, COS, SIN, KV, KMEAN);
  // 8. attn core -> BA (MFMA, 1 wave = 16 pos x 32 out)
  attn_mfma<<<GATT, 256, 0, stream>>>(BQ, KMEAN, KV, COS, SIN, BA);
  // 9. attn += lepe(h)
  dwconv4<2><<<GDW4, 256, 0, stream>>>(B3, lepe_w, lepe_b, BA);
  // 10. x2 = x1 + (attn*act_res)@outp + b -> A1 (fp16)
  mfma_gemm<CC0,CC0,64,1,5><<<dim3(MROWS/BM,CC0/64), 256, 0, stream>>>(BA, B1, outpT, outp_b, A0h, A1h, nullptr);
  // 11+12. x3 = x2 + cpe2(x2) -> A0 (fp16) ; xm = LN(x3) -> B0
  cpe_ln_kernel<f16><<<GPOS16, 256, 0, stream>>>(A1h, cpe2_w, cpe2_b, n2g, n2b, A0h, B0);
  // 13. f1 = xm@fc1 + b -> F1  (NB=128: halves A re-staging)
  mfma_gemm<CC0,C4,128,0,0><<<dim3(MROWS/BM,C4/128), 256, 0, stream>>>(B0, nullptr, fc1T, fc1_b, nullptr, F1, nullptr);
  // 14. fused: mdw conv + n1..n3 LN chain + gelu -> DW
  mdw_ln_kernel<<<GPOS16, 256, 0, stream>>>(F1, mdw_w, mdw_b, mn1g, mn1b, mn2g, mn2b, mn3g, mn3b, DW);
  // 15. out = x3 + gelu(n3)@fc2 + b (f32 out, fp16 addf)
  mfma_gemm<C4,CC0,64,0,3><<<dim3(MROWS/BM,CC0/64), 256, 0, stream>>>(DW, nullptr, fc2T, fc2_b, A0h, d_out, nullptr);
}

// Round 11
// 552.932 us; speedup vs baseline: 1.2210x; 1.2210x over previous
//
#include <hip/hip_runtime.h>
#include <hip/hip_bf16.h>
#include <hip/hip_fp16.h>
#include <math.h>

#define BB 16
#define HH 56
#define WW 56
#define CC0 192
#define NHH 6
#define HDD 32
#define NPOS (HH*WW)       // 3136
#define MROWS (BB*NPOS)    // 50176
#define C4 (4*CC0)         // 768

typedef __hip_bfloat16 bf16;
typedef __half f16;
typedef short short8 __attribute__((ext_vector_type(8)));
typedef short short4v __attribute__((ext_vector_type(4)));
typedef float f32x4 __attribute__((ext_vector_type(4)));
typedef float f32x2 __attribute__((ext_vector_type(2)));
typedef unsigned int u32;
typedef u32 u32x4 __attribute__((ext_vector_type(4)));
typedef u32 u32x2 __attribute__((ext_vector_type(2)));

__device__ __forceinline__ float b2f(bf16 v){ return __bfloat162float(v); }
__device__ __forceinline__ bf16 f2b(float v){ return __float2bfloat16(v); }
__device__ __forceinline__ short f2s(float v){ bf16 b = __float2bfloat16(v); return *(short*)&b; }
__device__ __forceinline__ float s2f(short s){ bf16 b; *(short*)&b = s; return __bfloat162float(b); }
__device__ __forceinline__ float tof(float v){ return v; }
__device__ __forceinline__ float tof(f16 v){ return __half2float(v); }
// unpack 2 bf16 (packed in u32) -> f32x2; exact (bit placement into high 16)
__device__ __forceinline__ f32x2 bfp(u32 u){
  union { u32 q; float f; } lo, hi;
  lo.q = u << 16; hi.q = u & 0xffff0000u;
  return (f32x2){lo.f, hi.f};
}
__device__ __forceinline__ float fast_gelu(float x){
  float u = 1.5957691216f * (x + 0.044715f*x*x*x);
  float t = 1.f - 2.f/(__expf(u) + 1.f);
  return 0.5f*x*(1.f + t);
}
// XCD-aware swizzle (verified R7: mdw_ln FETCH 164->38 MB)
__device__ __forceinline__ int swz8(int bid, int nblk){
  return (bid & 7) * (nblk >> 3) + (bid >> 3);
}

// ---------------- setup: weights f32->bf16 W^T, RoPE tables, zero KMEAN/KV ----------------
// R16: fused convert_weights + rope_tables + 2 memsets into one dispatch.
__global__ __launch_bounds__(256) void setup_kernel(
    const float* __restrict__ w0, const float* __restrict__ w1,
    const float* __restrict__ w2, const float* __restrict__ w3,
    const float* __restrict__ w4, const float* __restrict__ w5,
    short* __restrict__ dst, float* __restrict__ cosT, float* __restrict__ sinT,
    float* __restrict__ zbase){
  int bid = blockIdx.x;
  if (bid < 468){
    int e = (bid*256 + threadIdx.x)*4;
    const float* src; int K, N, off;
    if      (e <  36864){ src=w0; K=192; N=192; off=0; }
    else if (e <  73728){ src=w1; K=192; N=192; off=36864; }
    else if (e < 147456){ src=w2; K=192; N=384; off=73728; }
    else if (e < 184320){ src=w3; K=192; N=192; off=147456; }
    else if (e < 331776){ src=w4; K=192; N=768; off=184320; }
    else                { src=w5; K=768; N=192; off=331776; }
    int le = e - off;
    int n = le / K, k = le % K;
    short4v o;
    #pragma unroll
    for (int l = 0; l < 4; ++l) o[l] = f2s(src[(size_t)(k+l)*N + n]);
    *(short4v*)(dst + e) = o;
  } else if (bid < 468 + 1176){
    int idx = (bid-468)*256 + threadIdx.x;
    int t = idx % 96; int ij = idx / 96; int i = ij / WW; int j = ij % WW;
    int kk = (t < 48) ? t : (t - 48);
    float th = expf(-(float)kk * 0.19188209108283716f);
    float pos = (t < 48) ? (float)i : (float)j;
    float ang = pos * th;
    cosT[idx] = cosf(ang);
    sinT[idx] = sinf(ang);
  } else {
    int zi = ((bid-1644)*256 + threadIdx.x)*4;
    if (zi < 101376) *(f32x4*)(zbase + zi) = (f32x4){0.f,0.f,0.f,0.f};
  }
}

// ---------------- fused cpe dwconv + residual + LN192 (4 pos/wave) ----------------
// R11 structure; R15: templated input (f32 for x, fp16 for x2 spine),
// x1out stored fp16 (spine traffic halved; storage rounding only, accum f32).
template<typename TIN>
__global__ __launch_bounds__(256) void cpe_ln_kernel(const TIN* __restrict__ in,
    const float* __restrict__ w, const float* __restrict__ bias,
    const float* __restrict__ g, const float* __restrict__ bb,
    f16* __restrict__ x1out, bf16* __restrict__ xnout){
  int wv = threadIdx.x >> 6, lane = threadIdx.x & 63;
  int grp = swz8(blockIdx.x, gridDim.x)*4 + wv;   // group of 4 positions
  int pos0 = grp * 4;
  int b = pos0 / NPOS; int ij = pos0 % NPOS; int i = ij / WW; int j0 = ij % WW;
  int c = lane * 3;
  float acc[4][3];
  {
    float b0 = bias[c], b1 = bias[c+1], b2 = bias[c+2];
    #pragma unroll
    for (int p = 0; p < 4; ++p){ acc[p][0]=b0; acc[p][1]=b1; acc[p][2]=b2; }
  }
  float fc[4][3];                       // center-row in values (residual + LN re-add)
  bool leftOK  = (j0 > 0);
  bool rightOK = (j0 + 4 < WW);
  int base_i = (b*NPOS + i*WW + j0)*CC0 + c;   // elem offset (<9.7M, 32-bit safe)

  #pragma unroll
  for (int di = 0; di < 3; ++di){
    int ii = i + di - 1;
    if (ii < 0 || ii >= HH) continue;   // wave-uniform; OOB row contributes 0
    int rb = base_i + (di-1)*(WW*CC0);
    float wt[3][3];
    #pragma unroll
    for (int dj = 0; dj < 3; ++dj){
      const float* wp = w + (di*3 + dj)*CC0 + c;
      wt[dj][0] = wp[0]; wt[dj][1] = wp[1]; wt[dj][2] = wp[2];
    }
    if (leftOK){   // col 0: only (p=0, dj=0)
      const TIN* ip = in + rb - CC0;
      float d0 = tof(ip[0]), d1 = tof(ip[1]), d2 = tof(ip[2]);
      acc[0][0] += d0*wt[0][0]; acc[0][1] += d1*wt[0][1]; acc[0][2] += d2*wt[0][2];
    }
    #pragma unroll
    for (int col = 1; col <= 4; ++col){   // always in-bounds (j0 <= 52)
      const TIN* ip = in + rb + (col-1)*CC0;
      float d0 = tof(ip[0]), d1 = tof(ip[1]), d2 = tof(ip[2]);
      if (di == 1){ fc[col-1][0] = d0; fc[col-1][1] = d1; fc[col-1][2] = d2; }
      #pragma unroll
      for (int dj = 0; dj < 3; ++dj){
        int p = col - dj;
        if (p >= 0 && p < 4){
          acc[p][0] += d0*wt[dj][0]; acc[p][1] += d1*wt[dj][1]; acc[p][2] += d2*wt[dj][2];
        }
      }
    }
    if (rightOK){  // col 5: only (p=3, dj=2)
      const TIN* ip = in + rb + 4*CC0;
      float d0 = tof(ip[0]), d1 = tof(ip[1]), d2 = tof(ip[2]);
      acc[3][0] += d0*wt[2][0]; acc[3][1] += d1*wt[2][1]; acc[3][2] += d2*wt[2][2];
    }
  }
  float gv0 = g[c], gv1 = g[c+1], gv2 = g[c+2];
  float bv0 = bb[c], bv1 = bb[c+1], bv2 = bb[c+2];
  #pragma unroll
  for (int p = 0; p < 4; ++p){
    float v0 = fc[p][0] + acc[p][0];
    float v1 = fc[p][1] + acc[p][1];
    float v2 = fc[p][2] + acc[p][2];
    int base = (pos0 + p)*CC0 + c;
    f16* xp = x1out + base;
    xp[0] = __float2half(v0); xp[1] = __float2half(v1); xp[2] = __float2half(v2);
    float s = v0+v1+v2, q = v0*v0+v1*v1+v2*v2;
    #pragma unroll
    for (int m = 1; m < 64; m <<= 1){ s += __shfl_xor(s, m, 64); q += __shfl_xor(q, m, 64); }
    float mean = s * (1.f/CC0);
    float rstd = rsqrtf(q * (1.f/CC0) - mean*mean + 1e-5f);
    bf16* op = xnout + base;
    op[0] = f2b((v0-mean)*rstd*gv0 + bv0);
    op[1] = f2b((v1-mean)*rstd*gv1 + bv1);
    op[2] = f2b((v2-mean)*rstd*gv2 + bv2);
  }
}

// ---------------- depthwise 3x3 conv, 4 pos/thread, packed f32x2 (R12) ----------------
// MODE 1: out(bf16) = silu(conv+bias)   MODE 2: out(bf16) += conv+bias (RMW)
template<int MODE>
__global__ __launch_bounds__(256) void dwconv4(const bf16* __restrict__ in,
    const float* __restrict__ w, const float* __restrict__ bias, void* __restrict__ out){
  int idx = swz8(blockIdx.x, gridDim.x)*256 + threadIdx.x;
  int cg = idx % 24; int quad = idx / 24;
  int pos0 = quad * 4;
  int b = pos0 / NPOS; int ij = pos0 % NPOS; int i = ij / WW; int j0 = ij % WW;
  int cb = cg * 8;
  const short* fp = (const short*)in;
  f32x2 acc[4][4];
  {
    f32x2 bv0 = *(const f32x2*)(bias + cb);
    f32x2 bv1 = *(const f32x2*)(bias + cb + 2);
    f32x2 bv2 = *(const f32x2*)(bias + cb + 4);
    f32x2 bv3 = *(const f32x2*)(bias + cb + 6);
    #pragma unroll
    for (int p = 0; p < 4; ++p){ acc[p][0]=bv0; acc[p][1]=bv1; acc[p][2]=bv2; acc[p][3]=bv3; }
  }
  bool leftOK  = (j0 > 0);
  bool rightOK = (j0 + 4 < WW);
  int base_i = (b*NPOS + i*WW + j0)*CC0 + cb;   // elem offset (<9.7M, 32-bit safe)

  #pragma unroll
  for (int di = 0; di < 3; ++di){
    int ii = i + di - 1;
    if (ii < 0 || ii >= HH) continue;           // per-lane; OOB row contributes 0
    int rb = base_i + (di-1)*(WW*CC0);
    const float* wr = w + (di*3)*CC0 + cb;
    f32x2 wt[3][4];
    #pragma unroll
    for (int dj = 0; dj < 3; ++dj){
      #pragma unroll
      for (int l = 0; l < 4; ++l) wt[dj][l] = *(const f32x2*)(wr + dj*CC0 + 2*l);
    }
    if (leftOK){   // col 0: only (p=0, dj=0)
      u32x4 x = *(const u32x4*)(fp + rb - CC0);
      #pragma unroll
      for (int l = 0; l < 4; ++l) acc[0][l] += bfp(x[l])*wt[0][l];
    }
    #pragma unroll
    for (int col = 1; col <= 4; ++col){          // always in-bounds (j0 <= 52)
      u32x4 x = *(const u32x4*)(fp + rb + (col-1)*CC0);
      f32x2 dv[4];
      #pragma unroll
      for (int l = 0; l < 4; ++l) dv[l] = bfp(x[l]);
      #pragma unroll
      for (int dj = 0; dj < 3; ++dj){
        int p = col - dj;
        if (p >= 0 && p < 4){
          #pragma unroll
          for (int l = 0; l < 4; ++l) acc[p][l] += dv[l]*wt[dj][l];
        }
      }
    }
    if (rightOK){  // col 5: only (p=3, dj=2)
      u32x4 x = *(const u32x4*)(fp + rb + 4*CC0);
      #pragma unroll
      for (int l = 0; l < 4; ++l) acc[3][l] += bfp(x[l])*wt[2][l];
    }
  }
  #pragma unroll
  for (int p = 0; p < 4; ++p){
    int oidx = (pos0 + p)*CC0 + cb;
    short8 o;
    if constexpr (MODE == 1){
      #pragma unroll
      for (int l = 0; l < 4; ++l){
        float a0 = acc[p][l][0], a1 = acc[p][l][1];
        o[2*l]   = f2s(a0/(1.f + expf(-a0)));
        o[2*l+1] = f2s(a1/(1.f + expf(-a1)));
      }
    } else {
      u32x4 r = *(const u32x4*)((const short*)out + oidx);
      #pragma unroll
      for (int l = 0; l < 4; ++l){
        f32x2 s = bfp(r[l]) + acc[p][l];
        o[2*l] = f2s(s[0]); o[2*l+1] = f2s(s[1]);
      }
    }
    *(short8*)((short*)out + oidx) = o;
  }
}

// ---------------- MFMA GEMM: A [M,K] bf16-ish @ W^T [N,K] bf16 + bias ----------------
// R17: grid blockIdx.x = M-tile (fastest) — XCD round-robin partitions A-tiles
// across L2s; the tiny B-panel is resident everywhere. NB templated (128 = fc1).
// ALOAD: 0 = bf16 direct, 1 = bf16 * bf16 product
// EPI: 0 = bf16, 1 = silu->bf16, 2 = elu+1 split ->bf16,
//      3 = +addf(f16) -> f32, 4 = split silu/plain (addf = 2nd bias f32),
//      5 = +addf(f16) -> f16.  EPI 2/4 require NB=64 (n0 may not straddle 192).
#define BM 256
#define BK 32
#define LDA 40
template<int K, int N, int NB, int ALOAD, int EPI>
__global__ __launch_bounds__(256) void mfma_gemm(
    const void* __restrict__ a0v, const void* __restrict__ a1v,
    const short* __restrict__ wT, const float* __restrict__ bias,
    const void* __restrict__ addf, void* __restrict__ out0, void* __restrict__ out1){
  __shared__ short As[BM*LDA];
  __shared__ short Bs[NB*LDA];
  constexpr int NT = NB/16;
  int tid = threadIdx.x;
  int wave = tid >> 6, lane = tid & 63;
  size_t m0 = (size_t)blockIdx.x * BM;
  int n0 = blockIdx.y * NB;
  int wm = wave * 64;
  int am = lane & 15, ak = (lane >> 4) * 8;

  f32x4 acc[4][NT];
  #pragma unroll
  for (int mt = 0; mt < 4; ++mt)
    #pragma unroll
    for (int nt = 0; nt < NT; ++nt)
      acc[mt][nt] = (f32x4){0.f,0.f,0.f,0.f};

  for (int k0 = 0; k0 < K; k0 += BK){
    if constexpr (ALOAD == 0){
      const short* A = (const short*)a0v;
      #pragma unroll
      for (int it = 0; it < 4; ++it){
        int idx = it*256 + tid;
        int row = idx >> 2; int ko = (idx & 3) * 8;
        short8 v = *(const short8*)(A + (m0 + row)*(size_t)K + k0 + ko);
        *(short8*)&As[row*LDA + ko] = v;
      }
    } else {
      const short* A0p = (const short*)a0v;
      const short* A1p = (const short*)a1v;
      #pragma unroll
      for (int it = 0; it < 4; ++it){
        int idx = it*256 + tid;
        int row = idx >> 2; int ko = (idx & 3) * 8;
        size_t off = (m0 + row)*(size_t)K + k0 + ko;
        short8 va = *(const short8*)(A0p + off);
        short8 vb = *(const short8*)(A1p + off);
        short8 o;
        #pragma unroll
        for (int l = 0; l < 8; ++l) o[l] = f2s(s2f(va[l]) * s2f(vb[l]));
        *(short8*)&As[row*LDA + ko] = o;
      }
    }
    #pragma unroll
    for (int bt = 0; bt < NB/64; ++bt){
      int idx2 = bt*256 + tid;
      int row = idx2 >> 2; int ko = (idx2 & 3) * 8;
      short8 v = *(const short8*)(wT + (size_t)(n0 + row)*K + k0 + ko);
      *(short8*)&Bs[row*LDA + ko] = v;
    }
    __syncthreads();
    short8 af[4], bfr[NT];
    #pragma unroll
    for (int mt = 0; mt < 4; ++mt) af[mt] = *(short8*)&As[(wm + mt*16 + am)*LDA + ak];
    #pragma unroll
    for (int nt = 0; nt < NT; ++nt) bfr[nt] = *(short8*)&Bs[(nt*16 + am)*LDA + ak];
    #pragma unroll
    for (int mt = 0; mt < 4; ++mt)
      #pragma unroll
      for (int nt = 0; nt < NT; ++nt)
        acc[mt][nt] = __builtin_amdgcn_mfma_f32_16x16x32_bf16(af[mt], bfr[nt], acc[mt][nt], 0, 0, 0);
    __syncthreads();
  }

  int cn = lane & 15;
  int cr = (lane >> 4) * 4;
  #pragma unroll
  for (int mt = 0; mt < 4; ++mt){
    #pragma unroll
    for (int nt = 0; nt < NT; ++nt){
      int gn = n0 + nt*16 + cn;
      float bv;
      if constexpr (EPI == 4) bv = (n0 < CC0) ? bias[gn] : ((const float*)addf)[gn - CC0];
      else bv = bias[gn];
      #pragma unroll
      for (int r = 0; r < 4; ++r){
        size_t gm = m0 + wm + mt*16 + cr + r;
        float v = acc[mt][nt][r] + bv;
        if constexpr (EPI == 0){
          ((bf16*)out0)[gm*N + gn] = f2b(v);
        } else if constexpr (EPI == 1){
          ((bf16*)out0)[gm*N + gn] = f2b(v / (1.f + expf(-v)));
        } else if constexpr (EPI == 2){
          float rv = (v > 0.f) ? (v + 1.f) : expf(v);
          if (n0 < CC0) ((bf16*)out0)[gm*CC0 + gn] = f2b(rv);
          else          ((bf16*)out1)[gm*CC0 + (gn - CC0)] = f2b(rv);
        } else if constexpr (EPI == 4){
          if (n0 < CC0) ((bf16*)out0)[gm*CC0 + gn] = f2b(v / (1.f + expf(-v)));
          else          ((bf16*)out1)[gm*CC0 + (gn - CC0)] = f2b(v);
        } else if constexpr (EPI == 5){
          ((f16*)out0)[gm*N + gn] =
            __float2half(__half2float(((const f16*)addf)[gm*N + gn]) + v);
        } else {
          ((float*)out0)[gm*N + gn] =
            __half2float(((const f16*)addf)[gm*N + gn]) + v;
        }
      }
    }
  }
}

// ---------------- kv + kmean fused (R15), 14 N-chunks ----------------
#define KVCH 14
__global__ __launch_bounds__(256) void kv_kernel(const bf16* __restrict__ kbuf,
    const bf16* __restrict__ hbuf, const float* __restrict__ cosT,
    const float* __restrict__ sinT, float* __restrict__ kv,
    float* __restrict__ kmean){
  int bi = blockIdx.x;
  int chunk = bi % KVCH; bi /= KVCH;
  int h = bi % NHH; int b = bi / NHH;
  int tid = threadIdx.x;
  int r8 = tid >> 5, lane = tid & 31;
  __shared__ float krs[8][32];
  __shared__ float vvs[8][32];
  int d = tid >> 3; int ebase = (tid & 7) * 4;
  float a0 = 0.f, a1 = 0.f, a2 = 0.f, a3 = 0.f;
  float ksum = 0.f;
  int c = h*HDD + lane;
  int t = c >> 1;
  bool odd = (lane & 1);
  for (int step = 0; step < NPOS/(KVCH*8); ++step){
    int n = chunk*(NPOS/KVCH) + step*8 + r8;
    size_t row = (size_t)b*NPOS + n;
    float kc = b2f(kbuf[row*CC0 + c]);
    float kp = b2f(kbuf[row*CC0 + (c ^ 1)]);
    ksum += kc;
    float cs = cosT[(size_t)n*96 + t], sn = sinT[(size_t)n*96 + t];
    krs[r8][lane] = odd ? (cs*kc + sn*kp) : (cs*kc - sn*kp);
    vvs[r8][lane] = b2f(hbuf[row*CC0 + c]);
    __syncthreads();
    #pragma unroll
    for (int nn = 0; nn < 8; ++nn){
      float kk2 = krs[nn][d];
      a0 += kk2 * vvs[nn][ebase+0];
      a1 += kk2 * vvs[nn][ebase+1];
      a2 += kk2 * vvs[nn][ebase+2];
      a3 += kk2 * vvs[nn][ebase+3];
    }
    __syncthreads();
  }
  const float invN = 1.f/NPOS;
  ksum += __shfl_xor(ksum, 32, 64);
  if ((tid & 32) == 0) atomicAdd(&kmean[b*CC0 + c], ksum * invN);
  float* kvp = kv + (((size_t)(b*NHH + h)*HDD + d)*HDD) + ebase;
  atomicAdd(kvp+0, a0*invN);
  atomicAdd(kvp+1, a1*invN);
  atomicAdd(kvp+2, a2*invN);
  atomicAdd(kvp+3, a3*invN);
}

// ---------------- fused attention via MFMA (R14) ----------------
__global__ __launch_bounds__(256) void attn_mfma(const bf16* __restrict__ q,
    const float* __restrict__ kmean, const float* __restrict__ kv,
    const float* __restrict__ cosT, const float* __restrict__ sinT,
    bf16* __restrict__ out){
  int w = threadIdx.x >> 6, lane = threadIdx.x & 63;
  int idx = blockIdx.x*4 + w;            // tile index
  int mt = idx % (NPOS/16);              // 196 M-tiles
  int rest = idx / (NPOS/16);
  int h = rest % NHH; int b = rest / NHH;
  int r15 = lane & 15, kq = (lane >> 4) * 8;
  int n = mt*16 + r15;
  size_t row = (size_t)b*NPOS + n;
  int ch = h*HDD + kq;
  short8 q8 = *(const short8*)((const short*)q + row*CC0 + ch);
  float qf[8];
  #pragma unroll
  for (int j = 0; j < 8; ++j) qf[j] = s2f(q8[j]);
  const float* kmp = kmean + b*CC0 + ch;
  f32x4 km0 = *(const f32x4*)(kmp);
  f32x4 km1 = *(const f32x4*)(kmp + 4);
  float pm = qf[0]*km0[0]+qf[1]*km0[1]+qf[2]*km0[2]+qf[3]*km0[3]
           + qf[4]*km1[0]+qf[5]*km1[1]+qf[6]*km1[2]+qf[7]*km1[3];
  pm += __shfl_xor(pm, 16, 64);
  pm += __shfl_xor(pm, 32, 64);
  float z = 1.f/(pm + 1e-6f);
  int t0 = h*16 + (kq >> 1);
  f32x4 cs = *(const f32x4*)(cosT + n*96 + t0);
  f32x4 sn = *(const f32x4*)(sinT + n*96 + t0);
  short8 af;
  #pragma unroll
  for (int u = 0; u < 4; ++u){
    float e = cs[u]*qf[2*u]   - sn[u]*qf[2*u+1];
    float o = cs[u]*qf[2*u+1] + sn[u]*qf[2*u];
    af[2*u] = f2s(e); af[2*u+1] = f2s(o);
  }
  const float* kvp = kv + (size_t)(b*NHH + h)*HDD*HDD + kq*HDD + r15;
  short8 bf0, bf1;
  #pragma unroll
  for (int j = 0; j < 8; ++j){
    bf0[j] = f2s(kvp[j*HDD]);
    bf1[j] = f2s(kvp[j*HDD + 16]);
  }
  f32x4 acc0 = (f32x4){0.f,0.f,0.f,0.f};
  f32x4 acc1 = (f32x4){0.f,0.f,0.f,0.f};
  acc0 = __builtin_amdgcn_mfma_f32_16x16x32_bf16(af, bf0, acc0, 0, 0, 0);
  acc1 = __builtin_amdgcn_mfma_f32_16x16x32_bf16(af, bf1, acc1, 0, 0, 0);
  int rbase = (lane >> 4) * 4;
  #pragma unroll
  for (int r = 0; r < 4; ++r){
    float zz = __shfl(z, rbase + r, 64);
    size_t orow = (size_t)b*NPOS + mt*16 + rbase + r;
    out[orow*CC0 + ch - kq + r15]      = f2b(acc0[r]*zz);
    out[orow*CC0 + ch - kq + r15 + 16] = f2b(acc1[r]*zz);
  }
}

// ---------------- fused mdw dwconv + n1/n2/n3 LN chain + gelu (XCD-swizzled) ----------------
// R16: all 6 column loads of a conv row issued BEFORE any FMA (latency overlap);
// edge columns zero-filled (branch-free, 0-contribution == SAME padding).
// R10 packed-f32 math retained.
__global__ __launch_bounds__(256) void mdw_ln_kernel(const bf16* __restrict__ f1,
    const float* __restrict__ w, const float* __restrict__ bias,
    const float* __restrict__ g1, const float* __restrict__ b1,
    const float* __restrict__ g2, const float* __restrict__ b2,
    const float* __restrict__ g3, const float* __restrict__ b3,
    bf16* __restrict__ out){
  int wv = threadIdx.x >> 6, lane = threadIdx.x & 63;
  int grp = swz8(blockIdx.x, gridDim.x)*4 + wv;   // group of 4 positions
  int pos0 = grp * 4;
  int b = pos0 / NPOS; int ij = pos0 % NPOS; int i = ij / WW; int j0 = ij % WW;
  int c0 = lane * 8;
  int c1 = 512 + lane * 4;
  const short* fp = (const short*)f1;

  f32x2 acc2[4][6];
  {
    f32x2 bv[6];
    #pragma unroll
    for (int l = 0; l < 4; ++l) bv[l] = *(const f32x2*)(bias + c0 + 2*l);
    bv[4] = *(const f32x2*)(bias + c1);
    bv[5] = *(const f32x2*)(bias + c1 + 2);
    #pragma unroll
    for (int p = 0; p < 4; ++p)
      #pragma unroll
      for (int l = 0; l < 6; ++l) acc2[p][l] = bv[l];
  }
  u32x4 fca[4]; u32x2 fcb[4];   // center-row f1, packed bf16
  bool leftOK  = (j0 > 0);
  bool rightOK = (j0 + 4 < WW);
  int base_i = (b*NPOS + i*WW + j0)*C4;   // elem offset (<38.6M, 32-bit safe)

  #pragma unroll
  for (int di = 0; di < 3; ++di){
    int ii = i + di - 1;
    if (ii < 0 || ii >= HH) continue;     // wave-uniform; OOB row contributes 0
    int rb = base_i + (di-1)*(WW*C4);
    // batch-issue ALL 6 column loads before any FMA (R16)
    u32x4 xa6[6]; u32x2 xb6[6];
    if (leftOK){ xa6[0] = *(const u32x4*)(fp + rb - C4 + c0);
                 xb6[0] = *(const u32x2*)(fp + rb - C4 + c1); }
    else       { xa6[0] = (u32x4){0,0,0,0}; xb6[0] = (u32x2){0,0}; }
    #pragma unroll
    for (int col = 1; col <= 4; ++col){
      xa6[col] = *(const u32x4*)(fp + rb + (col-1)*C4 + c0);
      xb6[col] = *(const u32x2*)(fp + rb + (col-1)*C4 + c1);
    }
    if (rightOK){ xa6[5] = *(const u32x4*)(fp + rb + 4*C4 + c0);
                  xb6[5] = *(const u32x2*)(fp + rb + 4*C4 + c1); }
    else        { xa6[5] = (u32x4){0,0,0,0}; xb6[5] = (u32x2){0,0}; }
    f32x2 wt2[3][6];
    #pragma unroll
    for (int dj = 0; dj < 3; ++dj){
      const float* wp = w + (di*3 + dj)*C4;
      #pragma unroll
      for (int l = 0; l < 4; ++l) wt2[dj][l] = *(const f32x2*)(wp + c0 + 2*l);
      wt2[dj][4] = *(const f32x2*)(wp + c1);
      wt2[dj][5] = *(const f32x2*)(wp + c1 + 2);
    }
    #pragma unroll
    for (int col = 0; col < 6; ++col){
      if (di == 1 && col >= 1 && col <= 4){ fca[col-1] = xa6[col]; fcb[col-1] = xb6[col]; }
      f32x2 dv[6];
      dv[0]=bfp(xa6[col][0]); dv[1]=bfp(xa6[col][1]);
      dv[2]=bfp(xa6[col][2]); dv[3]=bfp(xa6[col][3]);
      dv[4]=bfp(xb6[col][0]); dv[5]=bfp(xb6[col][1]);
      #pragma unroll
      for (int dj = 0; dj < 3; ++dj){
        int p = col - dj;
        if (p >= 0 && p < 4){
          #pragma unroll
          for (int l = 0; l < 6; ++l) acc2[p][l] += dv[l]*wt2[dj][l];
        }
      }
    }
  }
  // v = dw + f1 (center residual)
  #pragma unroll
  for (int p = 0; p < 4; ++p){
    #pragma unroll
    for (int l = 0; l < 4; ++l) acc2[p][l] += bfp(fca[p][l]);
    acc2[p][4] += bfp(fcb[p][0]);
    acc2[p][5] += bfp(fcb[p][1]);
  }

  const float* gs[3] = {g1, g2, g3};
  const float* bs[3] = {b1, b2, b3};
  #pragma unroll
  for (int pass = 0; pass < 3; ++pass){
    f32x2 gv[6], bvv[6];
    #pragma unroll
    for (int l = 0; l < 4; ++l){
      gv[l]  = *(const f32x2*)(gs[pass] + c0 + 2*l);
      bvv[l] = *(const f32x2*)(bs[pass] + c0 + 2*l);
    }
    gv[4]  = *(const f32x2*)(gs[pass] + c1);  gv[5]  = *(const f32x2*)(gs[pass] + c1 + 2);
    bvv[4] = *(const f32x2*)(bs[pass] + c1);  bvv[5] = *(const f32x2*)(bs[pass] + c1 + 2);
    #pragma unroll
    for (int p = 0; p < 4; ++p){
      f32x2 s2 = acc2[p][0];
      f32x2 q2 = acc2[p][0]*acc2[p][0];
      #pragma unroll
      for (int l = 1; l < 6; ++l){ s2 += acc2[p][l]; q2 += acc2[p][l]*acc2[p][l]; }
      float s = s2[0]+s2[1], q = q2[0]+q2[1];
      #pragma unroll
      for (int m = 1; m < 64; m <<= 1){ s += __shfl_xor(s, m, 64); q += __shfl_xor(q, m, 64); }
      float mean = s * (1.f/C4);
      float rstd = rsqrtf(q * (1.f/C4) - mean*mean + 1e-5f);
      #pragma unroll
      for (int l = 0; l < 6; ++l){
        f32x2 rg = gv[l]*rstd;
        f32x2 t  = acc2[p][l] - mean;
        acc2[p][l] = t*rg + bvv[l];
      }
      if (pass < 2){
        #pragma unroll
        for (int l = 0; l < 4; ++l) acc2[p][l] += bfp(fca[p][l]);
        acc2[p][4] += bfp(fcb[p][0]);
        acc2[p][5] += bfp(fcb[p][1]);
      }
    }
  }
  #pragma unroll
  for (int p = 0; p < 4; ++p){
    short8 o0; short4v o1;
    #pragma unroll
    for (int l = 0; l < 4; ++l){
      o0[2*l]   = f2s(fast_gelu(acc2[p][l][0]));
      o0[2*l+1] = f2s(fast_gelu(acc2[p][l][1]));
    }
    o1[0] = f2s(fast_gelu(acc2[p][4][0]));
    o1[1] = f2s(fast_gelu(acc2[p][4][1]));
    o1[2] = f2s(fast_gelu(acc2[p][5][0]));
    o1[3] = f2s(fast_gelu(acc2[p][5][1]));
    int ob = (pos0 + p)*C4;
    *(short8*)((short*)out + ob + c0) = o0;
    *(short4v*)((short*)out + ob + c1) = o1;
  }
}

extern "C" void kernel_launch(void* const* d_in, const int* in_sizes, int n_in,
                              void* d_out, int out_size, void* d_ws, size_t ws_size,
                              hipStream_t stream){
  (void)in_sizes; (void)n_in; (void)out_size; (void)ws_size;
  const float* X      = (const float*)d_in[0];
  const float* cpe1_w = (const float*)d_in[1];
  const float* cpe1_b = (const float*)d_in[2];
  const float* n1g    = (const float*)d_in[3];
  const float* n1b    = (const float*)d_in[4];
  const float* in_w   = (const float*)d_in[5];
  const float* in_b   = (const float*)d_in[6];
  const float* actp_w = (const float*)d_in[7];
  const float* actp_b = (const float*)d_in[8];
  const float* dwc_w  = (const float*)d_in[9];
  const float* dwc_b  = (const float*)d_in[10];
  const float* qk_w   = (const float*)d_in[11];
  const float* qk_b   = (const float*)d_in[12];
  const float* lepe_w = (const float*)d_in[13];
  const float* lepe_b = (const float*)d_in[14];
  const float* outp_w = (const float*)d_in[15];
  const float* outp_b = (const float*)d_in[16];
  const float* cpe2_w = (const float*)d_in[17];
  const float* cpe2_b = (const float*)d_in[18];
  const float* n2g    = (const float*)d_in[19];
  const float* n2b    = (const float*)d_in[20];
  const float* fc1_w  = (const float*)d_in[21];
  const float* fc1_b  = (const float*)d_in[22];
  const float* mdw_w  = (const float*)d_in[23];
  const float* mdw_b  = (const float*)d_in[24];
  const float* fc2_w  = (const float*)d_in[25];
  const float* fc2_b  = (const float*)d_in[26];
  const float* mn1g   = (const float*)d_in[27];
  const float* mn1b   = (const float*)d_in[28];
  const float* mn2g   = (const float*)d_in[29];
  const float* mn2b   = (const float*)d_in[30];
  const float* mn3g   = (const float*)d_in[31];
  const float* mn3b   = (const float*)d_in[32];

  char* ws = (char*)d_ws;
  const size_t SZF = (size_t)MROWS*CC0*4;
  const size_t SZB = (size_t)MROWS*CC0*2;
  f16* A0h = (f16*)(ws);                    // x1 -> x3 (fp16 residual spine, R15)
  char* base2 = ws + SZF;
  bf16* BQ = (bf16*)(base2 + 0*SZB);        // q
  bf16* BKb= (bf16*)(base2 + 1*SZB);        // k
  bf16* BA = (bf16*)(base2 + 2*SZB);        // attn (+lepe)
  bf16* B1 = (bf16*)(base2 + 3*SZB);        // act_res
  bf16* B0 = (bf16*)(base2 + 4*SZB);        // xn -> xm
  bf16* B2 = (bf16*)(base2 + 5*SZB);        // t
  bf16* B3 = (bf16*)(base2 + 6*SZB);        // h
  f16*  A1h = (f16*)(base2);                // x2 (fp16) overlays BQ
  bf16*  F1 = (bf16*)(base2);               // f1 overlays slots 0-3
  bf16*  DW = (bf16*)(base2 + 4*SZB);       // gelu(n3) overlays slots 4-7
  short* WT = (short*)(base2 + 8*SZB);
  char* tail = (char*)(WT + 479232 + 64);
  float* KMEAN = (float*)tail;                 tail += (size_t)BB*CC0*4;
  float* KV    = (float*)tail;                 tail += (size_t)BB*NHH*HDD*HDD*4;
  float* COS   = (float*)tail;                 tail += (size_t)NPOS*96*4;
  float* SIN   = (float*)tail;

  const short* actpT = WT + 0;       // rows 0..191 = actp^T; rows 192..383 = in^T (contiguous)
  const short* qkT   = WT + 73728;
  const short* outpT = WT + 147456;
  const short* fc1T  = WT + 184320;
  const short* fc2T  = WT + 331776;

  const int GPOS16 = MROWS/16;             // 3136 (8 | G) — 4 waves x 4 pos
  const int GDW4   = (MROWS/4)*24/256;     // 1176 (8 | G) — dwconv4 grid
  const int GATT   = (BB*NHH*(NPOS/16))/4; // 4704 — attn_mfma grid (4 tiles/block)

  // 0. setup: weight convert + RoPE tables + zero KMEAN/KV (one dispatch, R16)
  setup_kernel<<<1743, 256, 0, stream>>>(actp_w, in_w, qk_w, outp_w, fc1_w, fc2_w,
                                         WT, COS, SIN, KMEAN);
  // 1+2. x1 = x + cpe1(x); xn = LN(x1)  (fused, 4 pos/wave, fp16 x1)
  cpe_ln_kernel<float><<<GPOS16, 256, 0, stream>>>(X, cpe1_w, cpe1_b, n1g, n1b, A0h, B0);
  // 3+4 fused. [act_res = silu(xn@actp)] ++ [t = xn@in_w + b]  (one N=384 GEMM)
  mfma_gemm<CC0,2*CC0,64,0,4><<<dim3(MROWS/BM,2*CC0/64), 256, 0, stream>>>(B0, nullptr, actpT, actp_b, in_b, B1, B2);
  // 5. h = silu(dwc(t))
  dwconv4<1><<<GDW4, 256, 0, stream>>>(B2, dwc_w, dwc_b, B3);
  // 6. qk = h@qk_w; q->BQ, k->BK (bf16, elu+1)
  mfma_gemm<CC0,2*CC0,64,0,2><<<dim3(MROWS/BM,2*CC0/64), 256, 0, stream>>>(B3, nullptr, qkT, qk_b, nullptr, BQ, BKb);
  // 7. kv + kmean (fused, R15)
  kv_kernel<<<BB*NHH*KVCH, 256, 0, stream>>>(BKb, B3, COS, SIN, KV, KMEAN);
  // 8. attn core -> BA (MFMA, 1 wave = 16 pos x 32 out)
  attn_mfma<<<GATT, 256, 0, stream>>>(BQ, KMEAN, KV, COS, SIN, BA);
  // 9. attn += lepe(h)
  dwconv4<2><<<GDW4, 256, 0, stream>>>(B3, lepe_w, lepe_b, BA);
  // 10. x2 = x1 + (attn*act_res)@outp + b -> A1 (fp16)
  mfma_gemm<CC0,CC0,64,1,5><<<dim3(MROWS/BM,CC0/64), 256, 0, stream>>>(BA, B1, outpT, outp_b, A0h, A1h, nullptr);
  // 11+12. x3 = x2 + cpe2(x2) -> A0 (fp16) ; xm = LN(x3) -> B0
  cpe_ln_kernel<f16><<<GPOS16, 256, 0, stream>>>(A1h, cpe2_w, cpe2_b, n2g, n2b, A0h, B0);
  // 13. f1 = xm@fc1 + b -> F1  (NB=128: halves A re-staging)
  mfma_gemm<CC0,C4,128,0,0><<<dim3(MROWS/BM,C4/128), 256, 0, stream>>>(B0, nullptr, fc1T, fc1_b, nullptr, F1, nullptr);
  // 14. fused: mdw conv + n1..n3 LN chain + gelu -> DW
  mdw_ln_kernel<<<GPOS16, 256, 0, stream>>>(F1, mdw_w, mdw_b, mn1g, mn1b, mn2g, mn2b, mn3g, mn3b, DW);
  // 15. out = x3 + gelu(n3)@fc2 + b (f32 out, fp16 addf)
  mfma_gemm<C4,CC0,64,0,3><<<dim3(MROWS/BM,CC0/64), 256, 0, stream>>>(DW, nullptr, fc2T, fc2_b, A0h, d_out, nullptr);
}